// Round 3
// baseline (481.748 us; speedup 1.0000x reference)
//
#include <hip/hip_runtime.h>

#define Bb 32
#define Ll 1024
#define LMD 1024
#define Dd 128
#define Rr 3
#define NLAYER 2
#define Cc 8
#define Nn (Bb*Ll)          // 32768
#define Ee 524288
#define NSEG (Nn*Rr)        // 98304
#define CAP 64              // slots per (node,relation); P(overflow) ~ 1e-40
#define LN_EPS 1e-5f

typedef __attribute__((ext_vector_type(8))) short bf16x8;
typedef __attribute__((ext_vector_type(4))) float f32x4;

__device__ inline short f2bf(float f) {
    unsigned u = __builtin_bit_cast(unsigned, f);
    u += 0x7fff + ((u >> 16) & 1);           // RNE
    return (short)(u >> 16);
}
__device__ inline float bf2f(unsigned short s) {
    unsigned u = ((unsigned)s) << 16;
    return __builtin_bit_cast(float, u);
}

// ---- prep: weight pack (blocks 0..1023, verbatim) + direct edge bucketing
// (blocks 1024..3071). fill pre-zeroed by memset; replaces hist+scan+scatter.
__global__ __launch_bounds__(256) void prep_kernel(
    const float* __restrict__ lmW, const float* __restrict__ Wrel,
    const float* __restrict__ Wroot, short* __restrict__ Wp_all,
    const int* __restrict__ src, const int* __restrict__ dst,
    const int* __restrict__ et,
    int* __restrict__ fill, int* __restrict__ slots)
{
    int bid = blockIdx.x;
    if (bid < 1024) {
        int idx = bid * 256 + threadIdx.x;   // 0..262143
        float v;
        if (idx < 131072) {
            int kk = idx & 31, n = (idx >> 5) & 127, ks = idx >> 12;
            v = lmW[n * 1024 + ks * 32 + kk];
        } else {
            int j = idx - 131072;
            int layer = j >> 16;
            int kk = j & 31, n = (j >> 5) & 127, ks = (j >> 12) & 15;
            int k = ks * 32 + kk;
            v = (k < 384) ? Wrel[(size_t)layer * 49152 + (size_t)k * 128 + n]
                          : Wroot[(size_t)layer * 16384 + (size_t)(k - 384) * 128 + n];
        }
        Wp_all[idx] = f2bf(v);
    } else {
        int e = (bid - 1024) * 256 + threadIdx.x;   // 0..Ee-1
        int s = dst[e] * 3 + et[e];
        int pos = atomicAdd(&fill[s], 1);
        if (pos < CAP) slots[(size_t)s * CAP + pos] = src[e];
    }
}

// ---- LM head GEMM (MFMA bf16) + bias + ReLU + fused LayerNorm (unchanged) ----
__global__ __launch_bounds__(256) void lm_gemm_ln_kernel(
    const float* __restrict__ A,        // [M,1024] fp32
    const short* __restrict__ Wp,       // [32][128][32] bf16 frag-packed
    const float* __restrict__ bias,     // [128]
    const float* __restrict__ lng, const float* __restrict__ lnb,
    short* __restrict__ lm_bf16)
{
    const int wv   = threadIdx.x >> 6;
    const int lane = threadIdx.x & 63;
    const int m16  = lane & 15;
    const int quad = lane >> 4;
    const int row_frag = blockIdx.x * 64 + wv * 16 + m16;
    const float* arow = A + (size_t)row_frag * 1024 + quad * 8;

    f32x4 acc[8];
    #pragma unroll
    for (int i = 0; i < 8; ++i) acc[i] = (f32x4){0.f, 0.f, 0.f, 0.f};

    #pragma unroll 2
    for (int ks = 0; ks < 32; ++ks) {
        const short* wpb = Wp + ks * 4096 + m16 * 32 + quad * 8;
        bf16x8 bfr[8];
        #pragma unroll
        for (int nt = 0; nt < 8; ++nt)
            bfr[nt] = *(const bf16x8*)(wpb + nt * 512);
        const float4* ap = (const float4*)(arow + ks * 32);
        float4 a0 = ap[0], a1 = ap[1];
        union { bf16x8 v; short s[8]; } af;
        af.s[0] = f2bf(a0.x); af.s[1] = f2bf(a0.y);
        af.s[2] = f2bf(a0.z); af.s[3] = f2bf(a0.w);
        af.s[4] = f2bf(a1.x); af.s[5] = f2bf(a1.y);
        af.s[6] = f2bf(a1.z); af.s[7] = f2bf(a1.w);
        #pragma unroll
        for (int nt = 0; nt < 8; ++nt)
            acc[nt] = __builtin_amdgcn_mfma_f32_16x16x32_bf16(af.v, bfr[nt], acc[nt], 0, 0, 0);
    }

    float v[8][4];
    #pragma unroll
    for (int nt = 0; nt < 8; ++nt) {
        float bs = bias[nt * 16 + m16];
        #pragma unroll
        for (int r = 0; r < 4; ++r) v[nt][r] = fmaxf(acc[nt][r] + bs, 0.f);
    }
    float gv[8], bv[8];
    #pragma unroll
    for (int nt = 0; nt < 8; ++nt) { gv[nt] = lng[nt * 16 + m16]; bv[nt] = lnb[nt * 16 + m16]; }

    const int row0 = blockIdx.x * 64 + wv * 16 + quad * 4;
    #pragma unroll
    for (int r = 0; r < 4; ++r) {
        float s = 0.f;
        #pragma unroll
        for (int nt = 0; nt < 8; ++nt) s += v[nt][r];
        s += __shfl_xor(s, 1, 64); s += __shfl_xor(s, 2, 64);
        s += __shfl_xor(s, 4, 64); s += __shfl_xor(s, 8, 64);
        float mu = s * (1.f / 128.f);
        float q = 0.f;
        #pragma unroll
        for (int nt = 0; nt < 8; ++nt) { float d = v[nt][r] - mu; q += d * d; }
        q += __shfl_xor(q, 1, 64); q += __shfl_xor(q, 2, 64);
        q += __shfl_xor(q, 4, 64); q += __shfl_xor(q, 8, 64);
        float rs = rsqrtf(q * (1.f / 128.f) + LN_EPS);
        size_t rowoff = (size_t)(row0 + r) * 128;
        #pragma unroll
        for (int nt = 0; nt < 8; ++nt) {
            float o = (v[nt][r] - mu) * rs * gv[nt] + bv[nt];
            lm_bf16[rowoff + nt * 16 + m16] = f2bf(o);
        }
    }
}

// ---- conv GEMM layer 1 (unchanged structure) ----
__global__ __launch_bounds__(256) void conv_gemm_kernel(
    const short* __restrict__ A1,       // [N,384] bf16 (agg)
    const short* __restrict__ A2,       // [N,128] bf16 (x)
    const short* __restrict__ Wp,       // [16][128][32] bf16 frag-packed
    const float* __restrict__ bias,
    short* __restrict__ out_bf16)       // [N,128]
{
    const int wv   = threadIdx.x >> 6;
    const int lane = threadIdx.x & 63;
    const int m16  = lane & 15;
    const int quad = lane >> 4;
    const int row_frag = blockIdx.x * 64 + wv * 16 + m16;
    const short* a1row = A1 + (size_t)row_frag * 384 + quad * 8;
    const short* a2row = A2 + (size_t)row_frag * 128 + quad * 8;

    f32x4 acc[8];
    #pragma unroll
    for (int i = 0; i < 8; ++i) acc[i] = (f32x4){0.f, 0.f, 0.f, 0.f};

    #pragma unroll 2
    for (int ks = 0; ks < 16; ++ks) {
        const short* wpb = Wp + ks * 4096 + m16 * 32 + quad * 8;
        bf16x8 bfr[8];
        #pragma unroll
        for (int nt = 0; nt < 8; ++nt)
            bfr[nt] = *(const bf16x8*)(wpb + nt * 512);
        const short* ar = (ks < 12) ? (a1row + ks * 32) : (a2row + (ks - 12) * 32);
        bf16x8 af = *(const bf16x8*)ar;
        #pragma unroll
        for (int nt = 0; nt < 8; ++nt)
            acc[nt] = __builtin_amdgcn_mfma_f32_16x16x32_bf16(af, bfr[nt], acc[nt], 0, 0, 0);
    }

    const int row0 = blockIdx.x * 64 + wv * 16 + quad * 4;
    #pragma unroll
    for (int nt = 0; nt < 8; ++nt) {
        float bs = bias[nt * 16 + m16];
        #pragma unroll
        for (int r = 0; r < 4; ++r) {
            float o = fmaxf(acc[nt][r] + bs, 0.f);
            out_bf16[(size_t)(row0 + r) * 128 + nt * 16 + m16] = f2bf(o);
        }
    }
}

// ---- conv GEMM layer 2 + classifier + masked CE loss, fused.
// g (= x2) stays in registers; never written to memory. Each 16-lane group
// owns one row: per-lane partial logits -> shfl_xor reduce over m16.
__global__ __launch_bounds__(256) void conv2_cls_kernel(
    const short* __restrict__ A1,       // [N,384] bf16 (agg)
    const short* __restrict__ A2,       // [N,128] bf16 (x1)
    const short* __restrict__ Wp,       // frag-packed conv weights layer 2
    const float* __restrict__ bias,     // conv_b[1]
    const float* __restrict__ clsW, const float* __restrict__ clsb,
    const short* __restrict__ lm,       // [N,128] bf16
    const int* __restrict__ mask, const int* __restrict__ labels,
    float* __restrict__ logits, float* __restrict__ accb,
    unsigned* __restrict__ ticket, float* __restrict__ loss_out)
{
    __shared__ float W[2048];           // clsW [8][256]
    for (int i = threadIdx.x; i < 2048; i += 256) W[i] = clsW[i];

    const int wv   = threadIdx.x >> 6;
    const int lane = threadIdx.x & 63;
    const int m16  = lane & 15;
    const int quad = lane >> 4;
    const int row_frag = blockIdx.x * 64 + wv * 16 + m16;
    const short* a1row = A1 + (size_t)row_frag * 384 + quad * 8;
    const short* a2row = A2 + (size_t)row_frag * 128 + quad * 8;

    f32x4 acc[8];
    #pragma unroll
    for (int i = 0; i < 8; ++i) acc[i] = (f32x4){0.f, 0.f, 0.f, 0.f};

    #pragma unroll 2
    for (int ks = 0; ks < 16; ++ks) {
        const short* wpb = Wp + ks * 4096 + m16 * 32 + quad * 8;
        bf16x8 bfr[8];
        #pragma unroll
        for (int nt = 0; nt < 8; ++nt)
            bfr[nt] = *(const bf16x8*)(wpb + nt * 512);
        const short* ar = (ks < 12) ? (a1row + ks * 32) : (a2row + (ks - 12) * 32);
        bf16x8 af = *(const bf16x8*)ar;
        #pragma unroll
        for (int nt = 0; nt < 8; ++nt)
            acc[nt] = __builtin_amdgcn_mfma_f32_16x16x32_bf16(af, bfr[nt], acc[nt], 0, 0, 0);
    }

    // bias + ReLU -> g in registers (x2 never materialized)
    float g[8][4];
    #pragma unroll
    for (int nt = 0; nt < 8; ++nt) {
        float bs = bias[nt * 16 + m16];
        #pragma unroll
        for (int r = 0; r < 4; ++r) g[nt][r] = fmaxf(acc[nt][r] + bs, 0.f);
    }

    __syncthreads();   // W (LDS) ready; writes overlapped with GEMM above

    const int row0 = blockIdx.x * 64 + wv * 16 + quad * 4;
    float lv = 0.f, cv = 0.f;

    #pragma unroll
    for (int r = 0; r < 4; ++r) {
        const int row = row0 + r;
        // lm slice: lane m16 loads cols [m16*8, m16*8+8)
        uint4 raw = *(const uint4*)(lm + (size_t)row * 128 + m16 * 8);
        float a[8];
        a[0] = bf2f((unsigned short)(raw.x & 0xffff)); a[1] = bf2f((unsigned short)(raw.x >> 16));
        a[2] = bf2f((unsigned short)(raw.y & 0xffff)); a[3] = bf2f((unsigned short)(raw.y >> 16));
        a[4] = bf2f((unsigned short)(raw.z & 0xffff)); a[5] = bf2f((unsigned short)(raw.z >> 16));
        a[6] = bf2f((unsigned short)(raw.w & 0xffff)); a[7] = bf2f((unsigned short)(raw.w >> 16));

        float p[8];
        #pragma unroll
        for (int c = 0; c < 8; ++c) {
            float s = 0.f;
            const float* w1 = &W[c * 256 + m16 * 8];
            #pragma unroll
            for (int j = 0; j < 8; ++j) s = fmaf(a[j], w1[j], s);
            const float* w2 = &W[c * 256 + 128 + m16];
            #pragma unroll
            for (int nt = 0; nt < 8; ++nt) s = fmaf(g[nt][r], w2[nt * 16], s);
            p[c] = s;
        }
        // reduce over the 16 lanes (m16) sharing this row
        #pragma unroll
        for (int c = 0; c < 8; ++c) {
            p[c] += __shfl_xor(p[c], 1, 64); p[c] += __shfl_xor(p[c], 2, 64);
            p[c] += __shfl_xor(p[c], 4, 64); p[c] += __shfl_xor(p[c], 8, 64);
            p[c] += clsb[c];
        }
        // write logits: lanes m16 0..7 write one float each (compile-time select)
        if (m16 < 8) {
            float o = p[0];
            #pragma unroll
            for (int c = 1; c < 8; ++c) o = (m16 == c) ? p[c] : o;
            logits[(size_t)row * 8 + m16] = o;
        }
        // softmax + NLL (redundant across the 16 lanes; only m16==0 accumulates)
        float mx = p[0];
        #pragma unroll
        for (int c = 1; c < 8; ++c) mx = fmaxf(mx, p[c]);
        float ss = 0.f;
        #pragma unroll
        for (int c = 0; c < 8; ++c) ss += expf(p[c] - mx);
        float lse = mx + logf(ss);
        int y = labels[row];
        float ly = p[0];
        #pragma unroll
        for (int c = 1; c < 8; ++c) ly = (y == c) ? p[c] : ly;
        bool valid = (mask[row] == 1);
        if (m16 == 0 && valid) { lv += lse - ly; cv += 1.f; }
    }

    #pragma unroll
    for (int off = 32; off > 0; off >>= 1) {
        lv += __shfl_down(lv, off, 64);
        cv += __shfl_down(cv, off, 64);
    }
    if (lane == 0) { atomicAdd(&accb[0], lv); atomicAdd(&accb[1], cv); }

    // last-block finalize; __syncthreads ensures ALL waves' adds are drained
    // before this block's ticket (fixes latent race in the old pattern)
    __threadfence();
    __syncthreads();
    if (threadIdx.x == 0) {
        unsigned t = atomicAdd(ticket, 1u);
        if (t == gridDim.x - 1) {
            float lsum = atomicAdd(&accb[0], 0.f);   // coherent read
            float csum = atomicAdd(&accb[1], 0.f);
            loss_out[0] = lsum / fmaxf(csum, 1.f);
        }
    }
}

// ---- per-(node,relation) mean aggregation over bf16 x (one wave/segment),
// now reading fixed-capacity buckets instead of compact CSR ----
__global__ __launch_bounds__(256) void aggregate_kernel(
    const short* __restrict__ x, const int* __restrict__ fill,
    const int* __restrict__ slots, short* __restrict__ agg)
{
    int seg  = blockIdx.x * 4 + (threadIdx.x >> 6);
    int lane = threadIdx.x & 63;
    int cnt = fill[seg];
    int e = cnt > CAP ? CAP : cnt;
    int n = seg / 3, r = seg - n * 3;
    const int* sl = slots + (size_t)seg * CAP;
    float ax = 0.f, ay = 0.f;
    int i = 0;
    for (; i + 4 <= e; i += 4) {
        int s0 = sl[i],     s1 = sl[i + 1];
        int s2 = sl[i + 2], s3 = sl[i + 3];
        unsigned u0 = *(const unsigned*)(x + (size_t)s0 * 128 + lane * 2);
        unsigned u1 = *(const unsigned*)(x + (size_t)s1 * 128 + lane * 2);
        unsigned u2 = *(const unsigned*)(x + (size_t)s2 * 128 + lane * 2);
        unsigned u3 = *(const unsigned*)(x + (size_t)s3 * 128 + lane * 2);
        ax += bf2f((unsigned short)(u0 & 0xffff)) + bf2f((unsigned short)(u1 & 0xffff))
            + bf2f((unsigned short)(u2 & 0xffff)) + bf2f((unsigned short)(u3 & 0xffff));
        ay += bf2f((unsigned short)(u0 >> 16)) + bf2f((unsigned short)(u1 >> 16))
            + bf2f((unsigned short)(u2 >> 16)) + bf2f((unsigned short)(u3 >> 16));
    }
    for (; i + 2 <= e; i += 2) {
        int s0 = sl[i], s1 = sl[i + 1];
        unsigned u0 = *(const unsigned*)(x + (size_t)s0 * 128 + lane * 2);
        unsigned u1 = *(const unsigned*)(x + (size_t)s1 * 128 + lane * 2);
        ax += bf2f((unsigned short)(u0 & 0xffff)) + bf2f((unsigned short)(u1 & 0xffff));
        ay += bf2f((unsigned short)(u0 >> 16))    + bf2f((unsigned short)(u1 >> 16));
    }
    if (i < e) {
        int s0 = sl[i];
        unsigned u0 = *(const unsigned*)(x + (size_t)s0 * 128 + lane * 2);
        ax += bf2f((unsigned short)(u0 & 0xffff));
        ay += bf2f((unsigned short)(u0 >> 16));
    }
    float inv = 1.f / (float)(cnt > 0 ? cnt : 1);
    unsigned short lo = (unsigned short)f2bf(ax * inv);
    unsigned short hi = (unsigned short)f2bf(ay * inv);
    *(unsigned*)(agg + (size_t)n * 384 + r * 128 + lane * 2) = (unsigned)lo | ((unsigned)hi << 16);
}

// ---- launcher ----
extern "C" void kernel_launch(void* const* d_in, const int* in_sizes, int n_in,
                              void* d_out, int out_size, void* d_ws, size_t ws_size,
                              hipStream_t stream)
{
    const float* output = (const float*)d_in[0];
    const int* edge_index = (const int*)d_in[1];
    const int* edge_type  = (const int*)d_in[2];
    const int* attn       = (const int*)d_in[3];
    const int* labels     = (const int*)d_in[4];
    const float* lmW   = (const float*)d_in[5];
    const float* lmb   = (const float*)d_in[6];
    const float* lng   = (const float*)d_in[7];
    const float* lnb   = (const float*)d_in[8];
    const float* Wrel  = (const float*)d_in[9];
    const float* Wroot = (const float*)d_in[10];
    const float* convb = (const float*)d_in[11];
    const float* clsW  = (const float*)d_in[12];
    const float* clsb  = (const float*)d_in[13];

    char* ws = (char*)d_ws;
    short* lm_bf  = (short*)ws;                          ws += (size_t)Nn * Dd * 2;
    short* x1_bf  = (short*)ws;                          ws += (size_t)Nn * Dd * 2;
    short* agg_bf = (short*)ws;                          ws += (size_t)Nn * 384 * 2;
    short* Wp_all = (short*)ws;                          ws += (size_t)262144 * 2;
    // zeroed region: [accb+ticket pad | fill] contiguous
    float* accb   = (float*)ws;                          ws += 64;
    int* fill     = (int*)ws;                            ws += (size_t)NSEG * 4;
    int* slots    = (int*)ws;                            // NSEG * CAP ints (25 MB)

    unsigned* ticket = (unsigned*)(accb + 2);            // inside zeroed pad

    short* Wp_lm = Wp_all;
    short* Wp_c0 = Wp_all + 131072;
    short* Wp_c1 = Wp_all + 131072 + 65536;

    const int* e_src = edge_index;
    const int* e_dst = edge_index + Ee;

    hipMemsetAsync(accb, 0, 64 + (size_t)NSEG * 4, stream);

    // pack weights + bucket edges (fused, independent halves)
    prep_kernel<<<dim3(1024 + Ee / 256), dim3(256), 0, stream>>>(
        lmW, Wrel, Wroot, Wp_all, e_src, e_dst, edge_type, fill, slots);

    // LM head + ReLU + fused LN (bf16 out only)
    lm_gemm_ln_kernel<<<dim3(Nn / 64), dim3(256), 0, stream>>>(
        output, Wp_lm, lmb, lng, lnb, lm_bf);

    // RGCN layer 1
    aggregate_kernel<<<dim3(NSEG / 4), dim3(256), 0, stream>>>(lm_bf, fill, slots, agg_bf);
    conv_gemm_kernel<<<dim3(Nn / 64), dim3(256), 0, stream>>>(
        agg_bf, lm_bf, Wp_c0, convb, x1_bf);

    // RGCN layer 2 fused with classifier + loss
    aggregate_kernel<<<dim3(NSEG / 4), dim3(256), 0, stream>>>(x1_bf, fill, slots, agg_bf);
    float* logits = (float*)d_out + 1;
    conv2_cls_kernel<<<dim3(Nn / 64), dim3(256), 0, stream>>>(
        agg_bf, x1_bf, Wp_c1, convb + Dd, clsW, clsb, lm_bf,
        attn, labels, logits, accb, ticket, (float*)d_out);
}

// Round 4
// 421.735 us; speedup vs baseline: 1.1423x; 1.1423x over previous
//
#include <hip/hip_runtime.h>

#define Bb 32
#define Ll 1024
#define LMD 1024
#define Dd 128
#define Rr 3
#define NLAYER 2
#define Cc 8
#define Nn (Bb*Ll)          // 32768
#define Ee 524288
#define NSEG (Nn*Rr)        // 98304
#define CAP 64              // slots per (node,relation); P(overflow) ~ 1e-40
#define NBLK 512            // Nn/64 — conv2_cls grid
#define LN_EPS 1e-5f

typedef __attribute__((ext_vector_type(8))) short bf16x8;
typedef __attribute__((ext_vector_type(4))) float f32x4;

__device__ inline short f2bf(float f) {
    unsigned u = __builtin_bit_cast(unsigned, f);
    u += 0x7fff + ((u >> 16) & 1);           // RNE
    return (short)(u >> 16);
}
__device__ inline float bf2f(unsigned short s) {
    unsigned u = ((unsigned)s) << 16;
    return __builtin_bit_cast(float, u);
}

// ---- prep: weight pack (blocks 0..1023, verbatim) + direct edge bucketing
// (blocks 1024..3071). fill pre-zeroed by memset; replaces hist+scan+scatter.
__global__ __launch_bounds__(256) void prep_kernel(
    const float* __restrict__ lmW, const float* __restrict__ Wrel,
    const float* __restrict__ Wroot, short* __restrict__ Wp_all,
    const int* __restrict__ src, const int* __restrict__ dst,
    const int* __restrict__ et,
    int* __restrict__ fill, int* __restrict__ slots)
{
    int bid = blockIdx.x;
    if (bid < 1024) {
        int idx = bid * 256 + threadIdx.x;   // 0..262143
        float v;
        if (idx < 131072) {
            int kk = idx & 31, n = (idx >> 5) & 127, ks = idx >> 12;
            v = lmW[n * 1024 + ks * 32 + kk];
        } else {
            int j = idx - 131072;
            int layer = j >> 16;
            int kk = j & 31, n = (j >> 5) & 127, ks = (j >> 12) & 15;
            int k = ks * 32 + kk;
            v = (k < 384) ? Wrel[(size_t)layer * 49152 + (size_t)k * 128 + n]
                          : Wroot[(size_t)layer * 16384 + (size_t)(k - 384) * 128 + n];
        }
        Wp_all[idx] = f2bf(v);
    } else {
        int e = (bid - 1024) * 256 + threadIdx.x;   // 0..Ee-1
        int s = dst[e] * 3 + et[e];
        int pos = atomicAdd(&fill[s], 1);
        if (pos < CAP) slots[(size_t)s * CAP + pos] = src[e];
    }
}

// ---- LM head GEMM (MFMA bf16) + bias + ReLU + fused LayerNorm (unchanged) ----
__global__ __launch_bounds__(256) void lm_gemm_ln_kernel(
    const float* __restrict__ A,        // [M,1024] fp32
    const short* __restrict__ Wp,       // [32][128][32] bf16 frag-packed
    const float* __restrict__ bias,     // [128]
    const float* __restrict__ lng, const float* __restrict__ lnb,
    short* __restrict__ lm_bf16)
{
    const int wv   = threadIdx.x >> 6;
    const int lane = threadIdx.x & 63;
    const int m16  = lane & 15;
    const int quad = lane >> 4;
    const int row_frag = blockIdx.x * 64 + wv * 16 + m16;
    const float* arow = A + (size_t)row_frag * 1024 + quad * 8;

    f32x4 acc[8];
    #pragma unroll
    for (int i = 0; i < 8; ++i) acc[i] = (f32x4){0.f, 0.f, 0.f, 0.f};

    #pragma unroll 2
    for (int ks = 0; ks < 32; ++ks) {
        const short* wpb = Wp + ks * 4096 + m16 * 32 + quad * 8;
        bf16x8 bfr[8];
        #pragma unroll
        for (int nt = 0; nt < 8; ++nt)
            bfr[nt] = *(const bf16x8*)(wpb + nt * 512);
        const float4* ap = (const float4*)(arow + ks * 32);
        float4 a0 = ap[0], a1 = ap[1];
        union { bf16x8 v; short s[8]; } af;
        af.s[0] = f2bf(a0.x); af.s[1] = f2bf(a0.y);
        af.s[2] = f2bf(a0.z); af.s[3] = f2bf(a0.w);
        af.s[4] = f2bf(a1.x); af.s[5] = f2bf(a1.y);
        af.s[6] = f2bf(a1.z); af.s[7] = f2bf(a1.w);
        #pragma unroll
        for (int nt = 0; nt < 8; ++nt)
            acc[nt] = __builtin_amdgcn_mfma_f32_16x16x32_bf16(af.v, bfr[nt], acc[nt], 0, 0, 0);
    }

    float v[8][4];
    #pragma unroll
    for (int nt = 0; nt < 8; ++nt) {
        float bs = bias[nt * 16 + m16];
        #pragma unroll
        for (int r = 0; r < 4; ++r) v[nt][r] = fmaxf(acc[nt][r] + bs, 0.f);
    }
    float gv[8], bv[8];
    #pragma unroll
    for (int nt = 0; nt < 8; ++nt) { gv[nt] = lng[nt * 16 + m16]; bv[nt] = lnb[nt * 16 + m16]; }

    const int row0 = blockIdx.x * 64 + wv * 16 + quad * 4;
    #pragma unroll
    for (int r = 0; r < 4; ++r) {
        float s = 0.f;
        #pragma unroll
        for (int nt = 0; nt < 8; ++nt) s += v[nt][r];
        s += __shfl_xor(s, 1, 64); s += __shfl_xor(s, 2, 64);
        s += __shfl_xor(s, 4, 64); s += __shfl_xor(s, 8, 64);
        float mu = s * (1.f / 128.f);
        float q = 0.f;
        #pragma unroll
        for (int nt = 0; nt < 8; ++nt) { float d = v[nt][r] - mu; q += d * d; }
        q += __shfl_xor(q, 1, 64); q += __shfl_xor(q, 2, 64);
        q += __shfl_xor(q, 4, 64); q += __shfl_xor(q, 8, 64);
        float rs = rsqrtf(q * (1.f / 128.f) + LN_EPS);
        size_t rowoff = (size_t)(row0 + r) * 128;
        #pragma unroll
        for (int nt = 0; nt < 8; ++nt) {
            float o = (v[nt][r] - mu) * rs * gv[nt] + bv[nt];
            lm_bf16[rowoff + nt * 16 + m16] = f2bf(o);
        }
    }
}

// ---- conv GEMM layer 1 (unchanged structure) ----
__global__ __launch_bounds__(256) void conv_gemm_kernel(
    const short* __restrict__ A1,       // [N,384] bf16 (agg)
    const short* __restrict__ A2,       // [N,128] bf16 (x)
    const short* __restrict__ Wp,       // [16][128][32] bf16 frag-packed
    const float* __restrict__ bias,
    short* __restrict__ out_bf16)       // [N,128]
{
    const int wv   = threadIdx.x >> 6;
    const int lane = threadIdx.x & 63;
    const int m16  = lane & 15;
    const int quad = lane >> 4;
    const int row_frag = blockIdx.x * 64 + wv * 16 + m16;
    const short* a1row = A1 + (size_t)row_frag * 384 + quad * 8;
    const short* a2row = A2 + (size_t)row_frag * 128 + quad * 8;

    f32x4 acc[8];
    #pragma unroll
    for (int i = 0; i < 8; ++i) acc[i] = (f32x4){0.f, 0.f, 0.f, 0.f};

    #pragma unroll 2
    for (int ks = 0; ks < 16; ++ks) {
        const short* wpb = Wp + ks * 4096 + m16 * 32 + quad * 8;
        bf16x8 bfr[8];
        #pragma unroll
        for (int nt = 0; nt < 8; ++nt)
            bfr[nt] = *(const bf16x8*)(wpb + nt * 512);
        const short* ar = (ks < 12) ? (a1row + ks * 32) : (a2row + (ks - 12) * 32);
        bf16x8 af = *(const bf16x8*)ar;
        #pragma unroll
        for (int nt = 0; nt < 8; ++nt)
            acc[nt] = __builtin_amdgcn_mfma_f32_16x16x32_bf16(af, bfr[nt], acc[nt], 0, 0, 0);
    }

    const int row0 = blockIdx.x * 64 + wv * 16 + quad * 4;
    #pragma unroll
    for (int nt = 0; nt < 8; ++nt) {
        float bs = bias[nt * 16 + m16];
        #pragma unroll
        for (int r = 0; r < 4; ++r) {
            float o = fmaxf(acc[nt][r] + bs, 0.f);
            out_bf16[(size_t)(row0 + r) * 128 + nt * 16 + m16] = f2bf(o);
        }
    }
}

// ---- conv GEMM layer 2 + classifier + masked CE loss, fused.
// NO fences, NO atomics: per-block (loss,count) partial -> plain float2 store.
__global__ __launch_bounds__(256) void conv2_cls_kernel(
    const short* __restrict__ A1,       // [N,384] bf16 (agg)
    const short* __restrict__ A2,       // [N,128] bf16 (x1)
    const short* __restrict__ Wp,       // frag-packed conv weights layer 2
    const float* __restrict__ bias,     // conv_b[1]
    const float* __restrict__ clsW, const float* __restrict__ clsb,
    const short* __restrict__ lm,       // [N,128] bf16
    const int* __restrict__ mask, const int* __restrict__ labels,
    float* __restrict__ logits, float2* __restrict__ partials)
{
    __shared__ float W[2048];           // clsW [8][256]
    __shared__ float2 wred[4];
    for (int i = threadIdx.x; i < 2048; i += 256) W[i] = clsW[i];

    const int wv   = threadIdx.x >> 6;
    const int lane = threadIdx.x & 63;
    const int m16  = lane & 15;
    const int quad = lane >> 4;
    const int row_frag = blockIdx.x * 64 + wv * 16 + m16;
    const short* a1row = A1 + (size_t)row_frag * 384 + quad * 8;
    const short* a2row = A2 + (size_t)row_frag * 128 + quad * 8;

    f32x4 acc[8];
    #pragma unroll
    for (int i = 0; i < 8; ++i) acc[i] = (f32x4){0.f, 0.f, 0.f, 0.f};

    #pragma unroll 2
    for (int ks = 0; ks < 16; ++ks) {
        const short* wpb = Wp + ks * 4096 + m16 * 32 + quad * 8;
        bf16x8 bfr[8];
        #pragma unroll
        for (int nt = 0; nt < 8; ++nt)
            bfr[nt] = *(const bf16x8*)(wpb + nt * 512);
        const short* ar = (ks < 12) ? (a1row + ks * 32) : (a2row + (ks - 12) * 32);
        bf16x8 af = *(const bf16x8*)ar;
        #pragma unroll
        for (int nt = 0; nt < 8; ++nt)
            acc[nt] = __builtin_amdgcn_mfma_f32_16x16x32_bf16(af, bfr[nt], acc[nt], 0, 0, 0);
    }

    // bias + ReLU -> g in registers (x2 never materialized)
    float g[8][4];
    #pragma unroll
    for (int nt = 0; nt < 8; ++nt) {
        float bs = bias[nt * 16 + m16];
        #pragma unroll
        for (int r = 0; r < 4; ++r) g[nt][r] = fmaxf(acc[nt][r] + bs, 0.f);
    }

    __syncthreads();   // W (LDS) ready; writes overlapped with GEMM above

    const int row0 = blockIdx.x * 64 + wv * 16 + quad * 4;
    float lv = 0.f, cv = 0.f;

    #pragma unroll
    for (int r = 0; r < 4; ++r) {
        const int row = row0 + r;
        // lm slice: lane m16 loads cols [m16*8, m16*8+8)
        uint4 raw = *(const uint4*)(lm + (size_t)row * 128 + m16 * 8);
        float a[8];
        a[0] = bf2f((unsigned short)(raw.x & 0xffff)); a[1] = bf2f((unsigned short)(raw.x >> 16));
        a[2] = bf2f((unsigned short)(raw.y & 0xffff)); a[3] = bf2f((unsigned short)(raw.y >> 16));
        a[4] = bf2f((unsigned short)(raw.z & 0xffff)); a[5] = bf2f((unsigned short)(raw.z >> 16));
        a[6] = bf2f((unsigned short)(raw.w & 0xffff)); a[7] = bf2f((unsigned short)(raw.w >> 16));

        float p[8];
        #pragma unroll
        for (int c = 0; c < 8; ++c) {
            float s = 0.f;
            const float* w1 = &W[c * 256 + m16 * 8];
            #pragma unroll
            for (int j = 0; j < 8; ++j) s = fmaf(a[j], w1[j], s);
            const float* w2 = &W[c * 256 + 128 + m16];
            #pragma unroll
            for (int nt = 0; nt < 8; ++nt) s = fmaf(g[nt][r], w2[nt * 16], s);
            p[c] = s;
        }
        // reduce over the 16 lanes (m16) sharing this row
        #pragma unroll
        for (int c = 0; c < 8; ++c) {
            p[c] += __shfl_xor(p[c], 1, 64); p[c] += __shfl_xor(p[c], 2, 64);
            p[c] += __shfl_xor(p[c], 4, 64); p[c] += __shfl_xor(p[c], 8, 64);
            p[c] += clsb[c];
        }
        // write logits: lanes m16 0..7 write one float each (compile-time select)
        if (m16 < 8) {
            float o = p[0];
            #pragma unroll
            for (int c = 1; c < 8; ++c) o = (m16 == c) ? p[c] : o;
            logits[(size_t)row * 8 + m16] = o;
        }
        // softmax + NLL (redundant across the 16 lanes; only m16==0 accumulates)
        float mx = p[0];
        #pragma unroll
        for (int c = 1; c < 8; ++c) mx = fmaxf(mx, p[c]);
        float ss = 0.f;
        #pragma unroll
        for (int c = 0; c < 8; ++c) ss += expf(p[c] - mx);
        float lse = mx + logf(ss);
        int y = labels[row];
        float ly = p[0];
        #pragma unroll
        for (int c = 1; c < 8; ++c) ly = (y == c) ? p[c] : ly;
        bool valid = (mask[row] == 1);
        if (m16 == 0 && valid) { lv += lse - ly; cv += 1.f; }
    }

    #pragma unroll
    for (int off = 32; off > 0; off >>= 1) {
        lv += __shfl_down(lv, off, 64);
        cv += __shfl_down(cv, off, 64);
    }
    if (lane == 0) wred[wv] = make_float2(lv, cv);
    __syncthreads();
    if (threadIdx.x == 0) {
        float2 p0 = wred[0], p1 = wred[1], p2 = wred[2], p3 = wred[3];
        partials[blockIdx.x] = make_float2(p0.x + p1.x + p2.x + p3.x,
                                           p0.y + p1.y + p2.y + p3.y);
    }
}

// ---- tiny finalize: reduce NBLK float2 partials -> loss scalar ----
__global__ __launch_bounds__(256) void loss_finalize_kernel(
    const float2* __restrict__ partials, float* __restrict__ loss_out)
{
    __shared__ float2 ws4[4];
    int t = threadIdx.x;
    float lv = 0.f, cv = 0.f;
    for (int i = t; i < NBLK; i += 256) { float2 p = partials[i]; lv += p.x; cv += p.y; }
    #pragma unroll
    for (int off = 32; off > 0; off >>= 1) {
        lv += __shfl_down(lv, off, 64);
        cv += __shfl_down(cv, off, 64);
    }
    if ((t & 63) == 0) ws4[t >> 6] = make_float2(lv, cv);
    __syncthreads();
    if (t == 0) {
        float ls = ws4[0].x + ws4[1].x + ws4[2].x + ws4[3].x;
        float cs = ws4[0].y + ws4[1].y + ws4[2].y + ws4[3].y;
        loss_out[0] = ls / fmaxf(cs, 1.f);
    }
}

// ---- per-(node,relation) mean aggregation over bf16 x (one wave/segment),
// reading fixed-capacity buckets ----
__global__ __launch_bounds__(256) void aggregate_kernel(
    const short* __restrict__ x, const int* __restrict__ fill,
    const int* __restrict__ slots, short* __restrict__ agg)
{
    int seg  = blockIdx.x * 4 + (threadIdx.x >> 6);
    int lane = threadIdx.x & 63;
    int cnt = fill[seg];
    int e = cnt > CAP ? CAP : cnt;
    int n = seg / 3, r = seg - n * 3;
    const int* sl = slots + (size_t)seg * CAP;
    float ax = 0.f, ay = 0.f;
    int i = 0;
    for (; i + 4 <= e; i += 4) {
        int s0 = sl[i],     s1 = sl[i + 1];
        int s2 = sl[i + 2], s3 = sl[i + 3];
        unsigned u0 = *(const unsigned*)(x + (size_t)s0 * 128 + lane * 2);
        unsigned u1 = *(const unsigned*)(x + (size_t)s1 * 128 + lane * 2);
        unsigned u2 = *(const unsigned*)(x + (size_t)s2 * 128 + lane * 2);
        unsigned u3 = *(const unsigned*)(x + (size_t)s3 * 128 + lane * 2);
        ax += bf2f((unsigned short)(u0 & 0xffff)) + bf2f((unsigned short)(u1 & 0xffff))
            + bf2f((unsigned short)(u2 & 0xffff)) + bf2f((unsigned short)(u3 & 0xffff));
        ay += bf2f((unsigned short)(u0 >> 16)) + bf2f((unsigned short)(u1 >> 16))
            + bf2f((unsigned short)(u2 >> 16)) + bf2f((unsigned short)(u3 >> 16));
    }
    for (; i + 2 <= e; i += 2) {
        int s0 = sl[i], s1 = sl[i + 1];
        unsigned u0 = *(const unsigned*)(x + (size_t)s0 * 128 + lane * 2);
        unsigned u1 = *(const unsigned*)(x + (size_t)s1 * 128 + lane * 2);
        ax += bf2f((unsigned short)(u0 & 0xffff)) + bf2f((unsigned short)(u1 & 0xffff));
        ay += bf2f((unsigned short)(u0 >> 16))    + bf2f((unsigned short)(u1 >> 16));
    }
    if (i < e) {
        int s0 = sl[i];
        unsigned u0 = *(const unsigned*)(x + (size_t)s0 * 128 + lane * 2);
        ax += bf2f((unsigned short)(u0 & 0xffff));
        ay += bf2f((unsigned short)(u0 >> 16));
    }
    float inv = 1.f / (float)(cnt > 0 ? cnt : 1);
    unsigned short lo = (unsigned short)f2bf(ax * inv);
    unsigned short hi = (unsigned short)f2bf(ay * inv);
    *(unsigned*)(agg + (size_t)n * 384 + r * 128 + lane * 2) = (unsigned)lo | ((unsigned)hi << 16);
}

// ---- launcher ----
extern "C" void kernel_launch(void* const* d_in, const int* in_sizes, int n_in,
                              void* d_out, int out_size, void* d_ws, size_t ws_size,
                              hipStream_t stream)
{
    const float* output = (const float*)d_in[0];
    const int* edge_index = (const int*)d_in[1];
    const int* edge_type  = (const int*)d_in[2];
    const int* attn       = (const int*)d_in[3];
    const int* labels     = (const int*)d_in[4];
    const float* lmW   = (const float*)d_in[5];
    const float* lmb   = (const float*)d_in[6];
    const float* lng   = (const float*)d_in[7];
    const float* lnb   = (const float*)d_in[8];
    const float* Wrel  = (const float*)d_in[9];
    const float* Wroot = (const float*)d_in[10];
    const float* convb = (const float*)d_in[11];
    const float* clsW  = (const float*)d_in[12];
    const float* clsb  = (const float*)d_in[13];

    char* ws = (char*)d_ws;
    short* lm_bf  = (short*)ws;                          ws += (size_t)Nn * Dd * 2;
    short* x1_bf  = (short*)ws;                          ws += (size_t)Nn * Dd * 2;
    short* agg_bf = (short*)ws;                          ws += (size_t)Nn * 384 * 2;
    short* Wp_all = (short*)ws;                          ws += (size_t)262144 * 2;
    float2* partials = (float2*)ws;                      ws += (size_t)NBLK * 8;
    int* fill     = (int*)ws;                            ws += (size_t)NSEG * 4;
    int* slots    = (int*)ws;                            // NSEG * CAP ints (25 MB)

    short* Wp_lm = Wp_all;
    short* Wp_c0 = Wp_all + 131072;
    short* Wp_c1 = Wp_all + 131072 + 65536;

    const int* e_src = edge_index;
    const int* e_dst = edge_index + Ee;

    hipMemsetAsync(fill, 0, (size_t)NSEG * 4, stream);

    // pack weights + bucket edges (fused, independent halves)
    prep_kernel<<<dim3(1024 + Ee / 256), dim3(256), 0, stream>>>(
        lmW, Wrel, Wroot, Wp_all, e_src, e_dst, edge_type, fill, slots);

    // LM head + ReLU + fused LN (bf16 out only)
    lm_gemm_ln_kernel<<<dim3(Nn / 64), dim3(256), 0, stream>>>(
        output, Wp_lm, lmb, lng, lnb, lm_bf);

    // RGCN layer 1
    aggregate_kernel<<<dim3(NSEG / 4), dim3(256), 0, stream>>>(lm_bf, fill, slots, agg_bf);
    conv_gemm_kernel<<<dim3(Nn / 64), dim3(256), 0, stream>>>(
        agg_bf, lm_bf, Wp_c0, convb, x1_bf);

    // RGCN layer 2 fused with classifier + loss partials
    aggregate_kernel<<<dim3(NSEG / 4), dim3(256), 0, stream>>>(x1_bf, fill, slots, agg_bf);
    float* logits = (float*)d_out + 1;
    conv2_cls_kernel<<<dim3(Nn / 64), dim3(256), 0, stream>>>(
        agg_bf, x1_bf, Wp_c1, convb + Dd, clsW, clsb, lm_bf,
        attn, labels, logits, partials);

    // tiny finalize (kernel boundary = visibility fence; no atomics anywhere)
    loss_finalize_kernel<<<dim3(1), dim3(256), 0, stream>>>(partials, (float*)d_out);
}